// Round 1
// 1035.894 us; speedup vs baseline: 1.3337x; 1.3337x over previous
//
#include <hip/hip_runtime.h>
#include <hip/hip_bf16.h>

#define N_NODES 100000
#define N_EDGES 1600000
#define D_IN    480
#define D_OUT   256
#define NEG_SLOPE 0.2f
#define NKB     (D_IN / 32)   // 15 K-steps of 32

typedef __attribute__((ext_vector_type(8))) short bf16x8;
typedef __attribute__((ext_vector_type(4))) float f32x4;

// ---- fp32 -> bf16 hi/lo split (round-to-nearest-even) --------------------
__device__ __forceinline__ unsigned short f2bf_rn(float f) {
    unsigned u = __float_as_uint(f);
    return (unsigned short)((u + 0x7fffu + ((u >> 16) & 1u)) >> 16);
}

__device__ __forceinline__ void split_bf16(float f, unsigned short& h, unsigned short& l) {
    unsigned u  = __float_as_uint(f);
    unsigned hr = (u + 0x7fffu + ((u >> 16) & 1u)) >> 16;
    h = (unsigned short)hr;
    float fh = __uint_as_float(hr << 16);
    l = f2bf_rn(f - fh);   // f - fh exact in fp32 (Sterbenz)
}

// ---- W pre-pack: [kb][col 0..511][kk 0..31] bf16 hi/lo -------------------
// col 0..255 = W_l, 256..511 = W_r. Fragment-native: lane reads 8 contiguous
// kk at (lane>>4)*8 for col = base + (lane&15)  -> 16B coalesced per colfrag.
__global__ __launch_bounds__(256) void pack_w(
    const float* __restrict__ Wl, const float* __restrict__ Wr,
    unsigned short* __restrict__ whi, unsigned short* __restrict__ wlo)
{
    const int idx = blockIdx.x * 256 + threadIdx.x;
    if (idx >= D_IN * 512) return;
    const int k   = idx >> 9;
    const int col = idx & 511;
    const float f = (col < 256) ? Wl[(size_t)k * 256 + col]
                                : Wr[(size_t)k * 256 + (col - 256)];
    unsigned short h, l;
    split_bf16(f, h, l);
    const size_t o = ((size_t)((k >> 5) * 512 + col) << 5) | (size_t)(k & 31);
    whi[o] = h; wlo[o] = l;
}

// ---- dual GEMM via bf16x3 MFMA -------------------------------------------
// 512 threads = 8 waves; wave w owns 64 rows x 64 cols (w<4 -> x_l, else x_r).
// A tile 64x32 staged fp32->hi/lo bf16 in LDS (double-buffered, XOR-swizzled
// 16B granules: byte = row*64 + (g ^ ((row>>1)&3))*16). B frags read directly
// from the packed W arrays (1 MB, L2-resident) -> no B LDS, x split once.
__global__ __launch_bounds__(512) void gemm_mfma(
    const float* __restrict__ x,
    const unsigned short* __restrict__ whi,
    const unsigned short* __restrict__ wlo,
    const float* __restrict__ b_l, const float* __restrict__ b_r,
    float* __restrict__ yl, float* __restrict__ yr)
{
    __shared__ __align__(16) unsigned short Ahi[2][64 * 32];
    __shared__ __align__(16) unsigned short Alo[2][64 * 32];

    const int t    = threadIdx.x;
    const int wid  = t >> 6;
    const int lane = t & 63;
    const int r0   = blockIdx.x * 64;

    // staging role: thread -> (row, 4 consecutive k)
    const int srow = t >> 3;
    const int sk4  = (t & 7) * 4;
    const int gr   = r0 + srow;
    const float* xrow   = x + (size_t)gr * D_IN;
    const bool  srow_ok = (gr < N_NODES);

    // swizzled write offset (ushort units): row*32 + (g ^ ((row>>1)&3))*8 + (k&7)
    const int woff = srow * 32 + (((sk4 >> 3) ^ ((srow >> 1) & 3)) * 8) + (sk4 & 7);

    const int l15 = lane & 15;
    const int lg  = lane >> 4;

    // A-frag read offsets per row-fragment (same swizzle)
    int aoff[4];
    #pragma unroll
    for (int rf = 0; rf < 4; ++rf) {
        const int row = rf * 16 + l15;
        aoff[rf] = row * 32 + ((lg ^ ((row >> 1) & 3)) * 8);
    }

    f32x4 acc[4][4] = {};

    float4 xv = make_float4(0.f, 0.f, 0.f, 0.f);
    if (srow_ok) xv = *(const float4*)(xrow + sk4);

    for (int kb = 0; kb < NKB; ++kb) {
        const int p = kb & 1;
        {   // split + LDS write (8B per array per thread)
            unsigned short h0,h1,h2,h3,l0,l1,l2,l3;
            split_bf16(xv.x, h0, l0); split_bf16(xv.y, h1, l1);
            split_bf16(xv.z, h2, l2); split_bf16(xv.w, h3, l3);
            *(uint2*)&Ahi[p][woff] = make_uint2((unsigned)h0 | ((unsigned)h1 << 16),
                                                (unsigned)h2 | ((unsigned)h3 << 16));
            *(uint2*)&Alo[p][woff] = make_uint2((unsigned)l0 | ((unsigned)l1 << 16),
                                                (unsigned)l2 | ((unsigned)l3 << 16));
        }
        // prefetch next x tile while this one is consumed
        float4 xv_next = make_float4(0.f, 0.f, 0.f, 0.f);
        if (kb + 1 < NKB && srow_ok)
            xv_next = *(const float4*)(xrow + (kb + 1) * 32 + sk4);

        __syncthreads();   // single barrier per K-step (double-buffered A)

        bf16x8 ah[4], al[4];
        #pragma unroll
        for (int rf = 0; rf < 4; ++rf) {
            ah[rf] = *(const bf16x8*)&Ahi[p][aoff[rf]];
            al[rf] = *(const bf16x8*)&Alo[p][aoff[rf]];
        }

        const size_t bbase = ((size_t)kb * 512 + wid * 64 + l15) * 32 + lg * 8;
        #pragma unroll
        for (int cf = 0; cf < 4; ++cf) {
            const size_t bo = bbase + (size_t)cf * 16 * 32;
            const bf16x8 bh = *(const bf16x8*)(whi + bo);
            const bf16x8 bl = *(const bf16x8*)(wlo + bo);
            #pragma unroll
            for (int rf = 0; rf < 4; ++rf) {
                acc[rf][cf] = __builtin_amdgcn_mfma_f32_16x16x32_bf16(ah[rf], bh, acc[rf][cf], 0, 0, 0);
                acc[rf][cf] = __builtin_amdgcn_mfma_f32_16x16x32_bf16(al[rf], bh, acc[rf][cf], 0, 0, 0);
                acc[rf][cf] = __builtin_amdgcn_mfma_f32_16x16x32_bf16(ah[rf], bl, acc[rf][cf], 0, 0, 0);
            }
        }
        xv = xv_next;
    }

    // epilogue: C/D layout col = lane&15, row = (lane>>4)*4 + i  [verified]
    float* const y  = (wid < 4) ? yl : yr;
    const float* bp = (wid < 4) ? b_l : b_r;
    #pragma unroll
    for (int cf = 0; cf < 4; ++cf) {
        const int ocol  = (wid & 3) * 64 + cf * 16 + l15;
        const float bia = bp[ocol];
        #pragma unroll
        for (int rf = 0; rf < 4; ++rf) {
            const int row0 = r0 + rf * 16 + lg * 4;
            #pragma unroll
            for (int i = 0; i < 4; ++i) {
                if (row0 + i < N_NODES)
                    y[(size_t)(row0 + i) * D_OUT + ocol] = acc[rf][cf][i] + bia;
            }
        }
    }
}

// ----------------------------------------------------------- CSR build ----
__global__ void init_csr(unsigned* __restrict__ deg, unsigned* __restrict__ total)
{
    const int i = blockIdx.x * 256 + threadIdx.x;
    if (i < N_NODES) deg[i] = 0u;
    if (i == 0) *total = 0u;
}

__global__ void hist_k(const int* __restrict__ ei, unsigned* __restrict__ deg)
{
    const int e = blockIdx.x * 256 + threadIdx.x;
    if (e < N_EDGES) atomicAdd(&deg[ei[N_EDGES + e]], 1u);
}

// per-wave shuffle scan of degrees; one global atomic per wave for the base
__global__ void row_start_k(const unsigned* __restrict__ deg,
                            unsigned* __restrict__ row_start,
                            unsigned* __restrict__ cursor,
                            unsigned* __restrict__ total)
{
    const int i    = blockIdx.x * 256 + threadIdx.x;
    const int lane = threadIdx.x & 63;
    const unsigned d = (i < N_NODES) ? deg[i] : 0u;

    unsigned v = d;
    #pragma unroll
    for (int off = 1; off < 64; off <<= 1) {
        unsigned tt = __shfl_up(v, off, 64);
        if (lane >= off) v += tt;
    }
    const unsigned excl = v - d;
    const unsigned wave_total = __shfl(v, 63, 64);

    unsigned base = 0;
    if (lane == 0) base = atomicAdd(total, wave_total);
    base = __shfl(base, 0, 64);

    if (i < N_NODES) {
        row_start[i] = base + excl;
        cursor[i]    = base + excl;
    }
}

__global__ void scatter_k(const int* __restrict__ ei,
                          unsigned* __restrict__ cursor,
                          int* __restrict__ csr_src)
{
    const int e = blockIdx.x * 256 + threadIdx.x;
    if (e >= N_EDGES) return;
    const int dst = ei[N_EDGES + e];
    const unsigned pos = atomicAdd(&cursor[dst], 1u);
    csr_src[pos] = ei[e];   // store SOURCE node id directly
}

// ---------------- fused node aggregate: logits + online softmax + gather --
// one 64-lane wave per dst node; lane owns 4 of 256 dims
__global__ __launch_bounds__(256) void node_agg(
    const float* __restrict__ xl, const float* __restrict__ xr,
    const float* __restrict__ att, const int* __restrict__ csr_src,
    const unsigned* __restrict__ row_start, const unsigned* __restrict__ deg,
    const float* __restrict__ bias, float* __restrict__ out)
{
    const int node = (blockIdx.x * blockDim.x + threadIdx.x) >> 6;
    const int lane = threadIdx.x & 63;
    if (node >= N_NODES) return;

    const int start = (int)row_start[node];
    const int cnt   = (int)deg[node];
    const int end   = start + cnt;

    const float4 a  = *(const float4*)(att + lane * 4);
    const float4 r  = *(const float4*)(xr + (size_t)node * D_OUT + lane * 4);

    float  m = -INFINITY;
    float  s = 0.f;
    float4 acc = make_float4(0.f, 0.f, 0.f, 0.f);

    float4 l = make_float4(0.f, 0.f, 0.f, 0.f);
    if (start < end)
        l = *(const float4*)(xl + (size_t)csr_src[start] * D_OUT + lane * 4);

    for (int j = start; j < end; ++j) {
        float4 l_next = make_float4(0.f, 0.f, 0.f, 0.f);
        if (j + 1 < end)
            l_next = *(const float4*)(xl + (size_t)csr_src[j + 1] * D_OUT + lane * 4);

        float h0 = l.x + r.x, h1 = l.y + r.y, h2 = l.z + r.z, h3 = l.w + r.w;
        h0 = h0 > 0.f ? h0 : NEG_SLOPE * h0;
        h1 = h1 > 0.f ? h1 : NEG_SLOPE * h1;
        h2 = h2 > 0.f ? h2 : NEG_SLOPE * h2;
        h3 = h3 > 0.f ? h3 : NEG_SLOPE * h3;
        float e = h0 * a.x + h1 * a.y + h2 * a.z + h3 * a.w;
        #pragma unroll
        for (int off = 32; off > 0; off >>= 1)
            e += __shfl_xor(e, off, 64);

        const float m_new = fmaxf(m, e);
        const float scale = __expf(m - m_new);
        const float p     = __expf(e - m_new);
        s = s * scale + p;
        acc.x = acc.x * scale + p * l.x;
        acc.y = acc.y * scale + p * l.y;
        acc.z = acc.z * scale + p * l.z;
        acc.w = acc.w * scale + p * l.w;
        m = m_new;

        l = l_next;
    }

    const float inv = 1.f / (s + 1e-16f);
    const float4 bv = *(const float4*)(bias + lane * 4);
    float4 o;
    o.x = acc.x * inv + bv.x; o.y = acc.y * inv + bv.y;
    o.z = acc.z * inv + bv.z; o.w = acc.w * inv + bv.w;
    *(float4*)(out + (size_t)node * D_OUT + lane * 4) = o;
}

// --------------------------------------------------------------- launch ---
extern "C" void kernel_launch(void* const* d_in, const int* in_sizes, int n_in,
                              void* d_out, int out_size, void* d_ws, size_t ws_size,
                              hipStream_t stream)
{
    const float* x   = (const float*)d_in[0];
    const int*   ei  = (const int*)  d_in[1];
    const float* W_l = (const float*)d_in[2];
    const float* b_l = (const float*)d_in[3];
    const float* W_r = (const float*)d_in[4];
    const float* b_r = (const float*)d_in[5];
    const float* att = (const float*)d_in[6];
    const float* bias= (const float*)d_in[7];
    float* out = (float*)d_out;

    // workspace layout (4-byte elements)
    float*    xl        = (float*)d_ws;                     // N*256
    float*    xr        = xl + (size_t)N_NODES * D_OUT;     // N*256
    int*      csr_src   = (int*)(xr + (size_t)N_NODES * D_OUT); // E
    unsigned* deg       = (unsigned*)(csr_src + N_EDGES);   // N
    unsigned* row_start = deg + N_NODES;                    // N
    unsigned* cursor    = row_start + N_NODES;              // N
    unsigned* total     = cursor + N_NODES;                 // 1 (+63 pad)
    unsigned short* whi = (unsigned short*)(total + 64);    // NKB*512*32 bf16
    unsigned short* wlo = whi + (size_t)NKB * 512 * 32;     // NKB*512*32 bf16

    // 0) pack W_l|W_r into bf16 hi/lo fragment-native layout (~1 MB, L2-resident)
    pack_w<<<(D_IN * 512 + 255) / 256, 256, 0, stream>>>(W_l, W_r, whi, wlo);

    // 1) x_l / x_r dual GEMM on the matrix pipe (bf16x3 fp32-emulation)
    gemm_mfma<<<(N_NODES + 63) / 64, 512, 0, stream>>>(
        x, whi, wlo, b_l, b_r, xl, xr);

    // 2) CSR build
    const int nb_nodes = (N_NODES + 255) / 256;
    const int nb_edges = (N_EDGES + 255) / 256;
    init_csr<<<nb_nodes, 256, 0, stream>>>(deg, total);
    hist_k<<<nb_edges, 256, 0, stream>>>(ei, deg);
    row_start_k<<<nb_nodes, 256, 0, stream>>>(deg, row_start, cursor, total);
    scatter_k<<<nb_edges, 256, 0, stream>>>(ei, cursor, csr_src);

    // 3) fused logits + softmax + aggregate (one wave per node)
    node_agg<<<(N_NODES + 3) / 4, 256, 0, stream>>>(
        xl, xr, att, csr_src, row_start, deg, bias, out);
}

// Round 2
// 966.269 us; speedup vs baseline: 1.4298x; 1.0721x over previous
//
#include <hip/hip_runtime.h>
#include <hip/hip_bf16.h>

#define N_NODES 100000
#define N_EDGES 1600000
#define D_IN    480
#define D_OUT   256
#define NEG_SLOPE 0.2f
#define NKB     (D_IN / 32)   // 15 K-steps of 32

typedef __attribute__((ext_vector_type(8))) short bf16x8;
typedef __attribute__((ext_vector_type(4))) float f32x4;

// ---- fp32 -> bf16 hi/lo split (round-to-nearest-even) --------------------
__device__ __forceinline__ unsigned short f2bf_rn(float f) {
    unsigned u = __float_as_uint(f);
    return (unsigned short)((u + 0x7fffu + ((u >> 16) & 1u)) >> 16);
}

__device__ __forceinline__ void split_bf16(float f, unsigned short& h, unsigned short& l) {
    unsigned u  = __float_as_uint(f);
    unsigned hr = (u + 0x7fffu + ((u >> 16) & 1u)) >> 16;
    h = (unsigned short)hr;
    float fh = __uint_as_float(hr << 16);
    l = f2bf_rn(f - fh);   // f - fh exact in fp32 (Sterbenz)
}

// ---- W pre-pack: [kb][col 0..511][kk 0..31] bf16 hi/lo -------------------
// col 0..255 = W_l, 256..511 = W_r. Fragment-native: lane reads 8 contiguous
// kk at (lane>>4)*8 for col = base + (lane&15)  -> 16B coalesced per colfrag.
__global__ __launch_bounds__(256) void pack_w(
    const float* __restrict__ Wl, const float* __restrict__ Wr,
    unsigned short* __restrict__ whi, unsigned short* __restrict__ wlo)
{
    const int idx = blockIdx.x * 256 + threadIdx.x;
    if (idx >= D_IN * 512) return;
    const int k   = idx >> 9;
    const int col = idx & 511;
    const float f = (col < 256) ? Wl[(size_t)k * 256 + col]
                                : Wr[(size_t)k * 256 + (col - 256)];
    unsigned short h, l;
    split_bf16(f, h, l);
    const size_t o = ((size_t)((k >> 5) * 512 + col) << 5) | (size_t)(k & 31);
    whi[o] = h; wlo[o] = l;
}

// ---- dual GEMM via bf16x3 MFMA, latency-hoisted K-loop -------------------
// 512 threads = 8 waves; wave w owns 64 rows x 64 cols (w<4 -> x_l, else x_r).
// Per K-step: [B loads][A ds_reads][stage next tile][prefetch x kb+2][MFMA]
// then ONE barrier -- all vmem was issued a full MFMA phase before the drain.
__global__ __launch_bounds__(512) void gemm_mfma(
    const float* __restrict__ x,
    const unsigned short* __restrict__ whi,
    const unsigned short* __restrict__ wlo,
    const float* __restrict__ b_l, const float* __restrict__ b_r,
    float* __restrict__ yl, float* __restrict__ yr)
{
    __shared__ __align__(16) unsigned short Ahi[2][64 * 32];
    __shared__ __align__(16) unsigned short Alo[2][64 * 32];

    const int t    = threadIdx.x;
    const int wid  = t >> 6;
    const int lane = t & 63;
    const int r0   = blockIdx.x * 64;

    // staging role: thread -> (row, 4 consecutive k)
    const int srow = t >> 3;
    const int sk4  = (t & 7) * 4;
    const int gr   = r0 + srow;
    const float* xrow   = x + (size_t)gr * D_IN;
    const bool  srow_ok = (gr < N_NODES);

    // swizzled offset (ushort units): row*32 + (g ^ ((row>>1)&3))*8 + (k&7)
    const int woff = srow * 32 + (((sk4 >> 3) ^ ((srow >> 1) & 3)) * 8) + (sk4 & 7);

    const int l15 = lane & 15;
    const int lg  = lane >> 4;

    int aoff[4];
    #pragma unroll
    for (int rf = 0; rf < 4; ++rf) {
        const int row = rf * 16 + l15;
        aoff[rf] = row * 32 + ((lg ^ ((row >> 1) & 3)) * 8);
    }

    f32x4 acc[4][4] = {};

    // ---- prologue: stage kb=0, issue prefetch of kb=1 --------------------
    {
        float4 xv = make_float4(0.f, 0.f, 0.f, 0.f);
        if (srow_ok) xv = *(const float4*)(xrow + sk4);
        unsigned short h0,h1,h2,h3,l0,l1,l2,l3;
        split_bf16(xv.x, h0, l0); split_bf16(xv.y, h1, l1);
        split_bf16(xv.z, h2, l2); split_bf16(xv.w, h3, l3);
        *(uint2*)&Ahi[0][woff] = make_uint2((unsigned)h0 | ((unsigned)h1 << 16),
                                            (unsigned)h2 | ((unsigned)h3 << 16));
        *(uint2*)&Alo[0][woff] = make_uint2((unsigned)l0 | ((unsigned)l1 << 16),
                                            (unsigned)l2 | ((unsigned)l3 << 16));
    }
    float4 xnext = make_float4(0.f, 0.f, 0.f, 0.f);
    if (srow_ok) xnext = *(const float4*)(xrow + 32 + sk4);
    __syncthreads();

    for (int kb = 0; kb < NKB; ++kb) {
        const int p = kb & 1;

        // (1) B fragment loads for THIS kb -- issued first, L2-resident
        const size_t bbase = ((size_t)kb * 512 + wid * 64 + l15) * 32 + lg * 8;
        bf16x8 bh[4], bl[4];
        #pragma unroll
        for (int cf = 0; cf < 4; ++cf) {
            bh[cf] = *(const bf16x8*)(whi + bbase + (size_t)cf * 512);
            bl[cf] = *(const bf16x8*)(wlo + bbase + (size_t)cf * 512);
        }

        // (2) A fragments from LDS buf[p]
        bf16x8 ah[4], al[4];
        #pragma unroll
        for (int rf = 0; rf < 4; ++rf) {
            ah[rf] = *(const bf16x8*)&Ahi[p][aoff[rf]];
            al[rf] = *(const bf16x8*)&Alo[p][aoff[rf]];
        }

        // (3) split + stage NEXT tile into buf[p^1]
        if (kb + 1 < NKB) {
            unsigned short h0,h1,h2,h3,l0,l1,l2,l3;
            split_bf16(xnext.x, h0, l0); split_bf16(xnext.y, h1, l1);
            split_bf16(xnext.z, h2, l2); split_bf16(xnext.w, h3, l3);
            *(uint2*)&Ahi[p ^ 1][woff] = make_uint2((unsigned)h0 | ((unsigned)h1 << 16),
                                                    (unsigned)h2 | ((unsigned)h3 << 16));
            *(uint2*)&Alo[p ^ 1][woff] = make_uint2((unsigned)l0 | ((unsigned)l1 << 16),
                                                    (unsigned)l2 | ((unsigned)l3 << 16));
        }

        // (4) issue x load for kb+2 -- a whole MFMA phase to land
        float4 xn2 = make_float4(0.f, 0.f, 0.f, 0.f);
        if (kb + 2 < NKB && srow_ok)
            xn2 = *(const float4*)(xrow + (kb + 2) * 32 + sk4);

        // (5) MFMA cluster, term-outer for 16-wide independent chains
        __builtin_amdgcn_s_setprio(1);
        #pragma unroll
        for (int cf = 0; cf < 4; ++cf)
            #pragma unroll
            for (int rf = 0; rf < 4; ++rf)
                acc[rf][cf] = __builtin_amdgcn_mfma_f32_16x16x32_bf16(ah[rf], bh[cf], acc[rf][cf], 0, 0, 0);
        #pragma unroll
        for (int cf = 0; cf < 4; ++cf)
            #pragma unroll
            for (int rf = 0; rf < 4; ++rf)
                acc[rf][cf] = __builtin_amdgcn_mfma_f32_16x16x32_bf16(al[rf], bh[cf], acc[rf][cf], 0, 0, 0);
        #pragma unroll
        for (int cf = 0; cf < 4; ++cf)
            #pragma unroll
            for (int rf = 0; rf < 4; ++rf)
                acc[rf][cf] = __builtin_amdgcn_mfma_f32_16x16x32_bf16(ah[rf], bl[cf], acc[rf][cf], 0, 0, 0);
        __builtin_amdgcn_s_setprio(0);

        // (6) single barrier per K-step
        __syncthreads();
        xnext = xn2;
    }

    // epilogue: C/D layout col = lane&15, row = (lane>>4)*4 + i  [verified]
    float* const y  = (wid < 4) ? yl : yr;
    const float* bp = (wid < 4) ? b_l : b_r;
    #pragma unroll
    for (int cf = 0; cf < 4; ++cf) {
        const int ocol  = (wid & 3) * 64 + cf * 16 + l15;
        const float bia = bp[ocol];
        #pragma unroll
        for (int rf = 0; rf < 4; ++rf) {
            const int row0 = r0 + rf * 16 + lg * 4;
            #pragma unroll
            for (int i = 0; i < 4; ++i) {
                if (row0 + i < N_NODES)
                    y[(size_t)(row0 + i) * D_OUT + ocol] = acc[rf][cf][i] + bia;
            }
        }
    }
}

// ----------------------------------------------------------- CSR build ----
__global__ void hist_k(const int* __restrict__ ei, unsigned* __restrict__ deg)
{
    const int e = blockIdx.x * 256 + threadIdx.x;
    if (e < N_EDGES) atomicAdd(&deg[ei[N_EDGES + e]], 1u);
}

// per-wave shuffle scan of degrees; one global atomic per wave for the base
__global__ void row_start_k(const unsigned* __restrict__ deg,
                            unsigned* __restrict__ row_start,
                            unsigned* __restrict__ cursor,
                            unsigned* __restrict__ total)
{
    const int i    = blockIdx.x * 256 + threadIdx.x;
    const int lane = threadIdx.x & 63;
    const unsigned d = (i < N_NODES) ? deg[i] : 0u;

    unsigned v = d;
    #pragma unroll
    for (int off = 1; off < 64; off <<= 1) {
        unsigned tt = __shfl_up(v, off, 64);
        if (lane >= off) v += tt;
    }
    const unsigned excl = v - d;
    const unsigned wave_total = __shfl(v, 63, 64);

    unsigned base = 0;
    if (lane == 0) base = atomicAdd(total, wave_total);
    base = __shfl(base, 0, 64);

    if (i < N_NODES) {
        row_start[i] = base + excl;
        cursor[i]    = base + excl;
    }
}

__global__ void scatter_k(const int* __restrict__ ei,
                          unsigned* __restrict__ cursor,
                          int* __restrict__ csr_src)
{
    const int e = blockIdx.x * 256 + threadIdx.x;
    if (e >= N_EDGES) return;
    const int dst = ei[N_EDGES + e];
    const unsigned pos = atomicAdd(&cursor[dst], 1u);
    csr_src[pos] = ei[e];   // store SOURCE node id directly
}

// ---------------- fused node aggregate: logits + online softmax + gather --
// one 64-lane wave per dst node; lane owns 4 of 256 dims.
// 2 edges per iteration: two independent shuffle chains overlap, softmax
// update amortized over the pair, 2-deep gather pipeline.
__global__ __launch_bounds__(256) void node_agg(
    const float* __restrict__ xl, const float* __restrict__ xr,
    const float* __restrict__ att, const int* __restrict__ csr_src,
    const unsigned* __restrict__ row_start, const unsigned* __restrict__ deg,
    const float* __restrict__ bias, float* __restrict__ out)
{
    const int node = (blockIdx.x * blockDim.x + threadIdx.x) >> 6;
    const int lane = threadIdx.x & 63;
    if (node >= N_NODES) return;

    const int start = (int)row_start[node];
    const int cnt   = (int)deg[node];
    const int end   = start + cnt;

    const float4 a  = *(const float4*)(att + lane * 4);
    const float4 r  = *(const float4*)(xr + (size_t)node * D_OUT + lane * 4);

    float  m = -INFINITY;
    float  s = 0.f;
    float4 acc = make_float4(0.f, 0.f, 0.f, 0.f);

    float4 lA = make_float4(0.f, 0.f, 0.f, 0.f);
    float4 lB = make_float4(0.f, 0.f, 0.f, 0.f);
    if (start     < end) lA = *(const float4*)(xl + (size_t)csr_src[start]     * D_OUT + lane * 4);
    if (start + 1 < end) lB = *(const float4*)(xl + (size_t)csr_src[start + 1] * D_OUT + lane * 4);

    int j = start;
    for (; j + 1 < end; j += 2) {
        float4 lC = make_float4(0.f, 0.f, 0.f, 0.f);
        float4 lD = make_float4(0.f, 0.f, 0.f, 0.f);
        if (j + 2 < end) lC = *(const float4*)(xl + (size_t)csr_src[j + 2] * D_OUT + lane * 4);
        if (j + 3 < end) lD = *(const float4*)(xl + (size_t)csr_src[j + 3] * D_OUT + lane * 4);

        float h0 = lA.x + r.x, h1 = lA.y + r.y, h2 = lA.z + r.z, h3 = lA.w + r.w;
        h0 = h0 > 0.f ? h0 : NEG_SLOPE * h0;
        h1 = h1 > 0.f ? h1 : NEG_SLOPE * h1;
        h2 = h2 > 0.f ? h2 : NEG_SLOPE * h2;
        h3 = h3 > 0.f ? h3 : NEG_SLOPE * h3;
        float e0 = h0 * a.x + h1 * a.y + h2 * a.z + h3 * a.w;

        float g0 = lB.x + r.x, g1 = lB.y + r.y, g2 = lB.z + r.z, g3 = lB.w + r.w;
        g0 = g0 > 0.f ? g0 : NEG_SLOPE * g0;
        g1 = g1 > 0.f ? g1 : NEG_SLOPE * g1;
        g2 = g2 > 0.f ? g2 : NEG_SLOPE * g2;
        g3 = g3 > 0.f ? g3 : NEG_SLOPE * g3;
        float e1 = g0 * a.x + g1 * a.y + g2 * a.z + g3 * a.w;

        #pragma unroll
        for (int off = 32; off > 0; off >>= 1) {
            e0 += __shfl_xor(e0, off, 64);
            e1 += __shfl_xor(e1, off, 64);
        }

        const float m_new = fmaxf(fmaxf(m, e0), e1);
        const float scale = __expf(m - m_new);
        const float p0    = __expf(e0 - m_new);
        const float p1    = __expf(e1 - m_new);
        s = s * scale + p0 + p1;
        acc.x = acc.x * scale + p0 * lA.x + p1 * lB.x;
        acc.y = acc.y * scale + p0 * lA.y + p1 * lB.y;
        acc.z = acc.z * scale + p0 * lA.z + p1 * lB.z;
        acc.w = acc.w * scale + p0 * lA.w + p1 * lB.w;
        m = m_new;

        lA = lC; lB = lD;
    }
    if (j < end) {   // odd tail
        float h0 = lA.x + r.x, h1 = lA.y + r.y, h2 = lA.z + r.z, h3 = lA.w + r.w;
        h0 = h0 > 0.f ? h0 : NEG_SLOPE * h0;
        h1 = h1 > 0.f ? h1 : NEG_SLOPE * h1;
        h2 = h2 > 0.f ? h2 : NEG_SLOPE * h2;
        h3 = h3 > 0.f ? h3 : NEG_SLOPE * h3;
        float e0 = h0 * a.x + h1 * a.y + h2 * a.z + h3 * a.w;
        #pragma unroll
        for (int off = 32; off > 0; off >>= 1)
            e0 += __shfl_xor(e0, off, 64);

        const float m_new = fmaxf(m, e0);
        const float scale = __expf(m - m_new);
        const float p0    = __expf(e0 - m_new);
        s = s * scale + p0;
        acc.x = acc.x * scale + p0 * lA.x;
        acc.y = acc.y * scale + p0 * lA.y;
        acc.z = acc.z * scale + p0 * lA.z;
        acc.w = acc.w * scale + p0 * lA.w;
        m = m_new;
    }

    const float inv = 1.f / (s + 1e-16f);
    const float4 bv = *(const float4*)(bias + lane * 4);
    float4 o;
    o.x = acc.x * inv + bv.x; o.y = acc.y * inv + bv.y;
    o.z = acc.z * inv + bv.z; o.w = acc.w * inv + bv.w;
    *(float4*)(out + (size_t)node * D_OUT + lane * 4) = o;
}

// --------------------------------------------------------------- launch ---
extern "C" void kernel_launch(void* const* d_in, const int* in_sizes, int n_in,
                              void* d_out, int out_size, void* d_ws, size_t ws_size,
                              hipStream_t stream)
{
    const float* x   = (const float*)d_in[0];
    const int*   ei  = (const int*)  d_in[1];
    const float* W_l = (const float*)d_in[2];
    const float* b_l = (const float*)d_in[3];
    const float* W_r = (const float*)d_in[4];
    const float* b_r = (const float*)d_in[5];
    const float* att = (const float*)d_in[6];
    const float* bias= (const float*)d_in[7];
    float* out = (float*)d_out;

    // workspace layout (4-byte elements); deg and total adjacent for memset
    float*    xl        = (float*)d_ws;                     // N*256
    float*    xr        = xl + (size_t)N_NODES * D_OUT;     // N*256
    int*      csr_src   = (int*)(xr + (size_t)N_NODES * D_OUT); // E
    unsigned* deg       = (unsigned*)(csr_src + N_EDGES);   // N
    unsigned* total     = deg + N_NODES;                    // 1 (+63 pad)
    unsigned* row_start = total + 64;                       // N
    unsigned* cursor    = row_start + N_NODES;              // N
    unsigned short* whi = (unsigned short*)(cursor + N_NODES); // NKB*512*32 bf16
    unsigned short* wlo = whi + (size_t)NKB * 512 * 32;     // NKB*512*32 bf16

    // 0) pack W_l|W_r into bf16 hi/lo fragment-native layout (~1 MB, L2-resident)
    pack_w<<<(D_IN * 512 + 255) / 256, 256, 0, stream>>>(W_l, W_r, whi, wlo);

    // 1) x_l / x_r dual GEMM on the matrix pipe (bf16x3 fp32-emulation)
    gemm_mfma<<<(N_NODES + 63) / 64, 512, 0, stream>>>(
        x, whi, wlo, b_l, b_r, xl, xr);

    // 2) CSR build (deg+total zeroed by one async memset; graph-capturable)
    hipMemsetAsync(deg, 0, (size_t)(N_NODES + 1) * sizeof(unsigned), stream);
    const int nb_nodes = (N_NODES + 255) / 256;
    const int nb_edges = (N_EDGES + 255) / 256;
    hist_k<<<nb_edges, 256, 0, stream>>>(ei, deg);
    row_start_k<<<nb_nodes, 256, 0, stream>>>(deg, row_start, cursor, total);
    scatter_k<<<nb_edges, 256, 0, stream>>>(ei, cursor, csr_src);

    // 3) fused logits + softmax + aggregate (one wave per node)
    node_agg<<<(N_NODES + 3) / 4, 256, 0, stream>>>(
        xl, xr, att, csr_src, row_start, deg, bias, out);
}

// Round 3
// 959.952 us; speedup vs baseline: 1.4392x; 1.0066x over previous
//
#include <hip/hip_runtime.h>
#include <hip/hip_bf16.h>

#define N_NODES 100000
#define N_EDGES 1600000
#define D_IN    480
#define D_OUT   256
#define NEG_SLOPE 0.2f
#define NKB     (D_IN / 32)   // 15 K-steps of 32

typedef __attribute__((ext_vector_type(8))) short bf16x8;
typedef __attribute__((ext_vector_type(4))) float f32x4;

// ---- fp32 -> bf16 hi/lo split (round-to-nearest-even) --------------------
__device__ __forceinline__ unsigned short f2bf_rn(float f) {
    unsigned u = __float_as_uint(f);
    return (unsigned short)((u + 0x7fffu + ((u >> 16) & 1u)) >> 16);
}

__device__ __forceinline__ void split_bf16(float f, unsigned short& h, unsigned short& l) {
    unsigned u  = __float_as_uint(f);
    unsigned hr = (u + 0x7fffu + ((u >> 16) & 1u)) >> 16;
    h = (unsigned short)hr;
    float fh = __uint_as_float(hr << 16);
    l = f2bf_rn(f - fh);   // f - fh exact in fp32 (Sterbenz)
}

// ---- W pre-pack: [kb][col 0..511][kk 0..31] bf16 hi/lo -------------------
__global__ __launch_bounds__(256) void pack_w(
    const float* __restrict__ Wl, const float* __restrict__ Wr,
    unsigned short* __restrict__ whi, unsigned short* __restrict__ wlo)
{
    const int idx = blockIdx.x * 256 + threadIdx.x;
    if (idx >= D_IN * 512) return;
    const int k   = idx >> 9;
    const int col = idx & 511;
    const float f = (col < 256) ? Wl[(size_t)k * 256 + col]
                                : Wr[(size_t)k * 256 + (col - 256)];
    unsigned short h, l;
    split_bf16(f, h, l);
    const size_t o = ((size_t)((k >> 5) * 512 + col) << 5) | (size_t)(k & 31);
    whi[o] = h; wlo[o] = l;
}

// ---- dual GEMM via bf16x3 MFMA, counted-wait barrier K-loop --------------
// 512 threads = 8 waves; wave w owns 64 rows x 64 cols (w<4 -> x_l, else x_r).
// Barrier is lgkmcnt(0)-only (raw s_barrier): global x prefetch (2 phases
// deep) stays in flight across barriers; compiler-counted vmcnt orders uses.
__global__ __launch_bounds__(512) void gemm_mfma(
    const float* __restrict__ x,
    const unsigned short* __restrict__ whi,
    const unsigned short* __restrict__ wlo,
    const float* __restrict__ b_l, const float* __restrict__ b_r,
    float* __restrict__ yl, float* __restrict__ yr)
{
    __shared__ __align__(16) unsigned short Ahi[2][64 * 32];
    __shared__ __align__(16) unsigned short Alo[2][64 * 32];

    const int t    = threadIdx.x;
    const int wid  = t >> 6;
    const int lane = t & 63;
    const int r0   = blockIdx.x * 64;

    // staging role: thread -> (row, 4 consecutive k)
    const int srow = t >> 3;
    const int sk4  = (t & 7) * 4;
    const int gr   = r0 + srow;
    const float* xrow   = x + (size_t)gr * D_IN;
    const bool  srow_ok = (gr < N_NODES);

    // swizzled offset (ushort units): row*32 + (g ^ ((row>>1)&3))*8 + (k&7)
    const int woff = srow * 32 + (((sk4 >> 3) ^ ((srow >> 1) & 3)) * 8) + (sk4 & 7);

    const int l15 = lane & 15;
    const int lg  = lane >> 4;

    int aoff[4];
    #pragma unroll
    for (int rf = 0; rf < 4; ++rf) {
        const int row = rf * 16 + l15;
        aoff[rf] = row * 32 + ((lg ^ ((row >> 1) & 3)) * 8);
    }

    f32x4 acc[4][4] = {};

    // ---- prologue: stage tile0; tiles 1,2 in flight ----------------------
    float4 xv  = make_float4(0.f, 0.f, 0.f, 0.f);
    float4 xq0 = make_float4(0.f, 0.f, 0.f, 0.f);
    float4 xq1 = make_float4(0.f, 0.f, 0.f, 0.f);
    if (srow_ok) {
        xv  = *(const float4*)(xrow + sk4);        // tile 0 (issued first)
        xq0 = *(const float4*)(xrow + 32 + sk4);   // tile 1
        xq1 = *(const float4*)(xrow + 64 + sk4);   // tile 2
    }
    {
        unsigned short h0,h1,h2,h3,l0,l1,l2,l3;
        split_bf16(xv.x, h0, l0); split_bf16(xv.y, h1, l1);
        split_bf16(xv.z, h2, l2); split_bf16(xv.w, h3, l3);
        *(uint2*)&Ahi[0][woff] = make_uint2((unsigned)h0 | ((unsigned)h1 << 16),
                                            (unsigned)h2 | ((unsigned)h3 << 16));
        *(uint2*)&Alo[0][woff] = make_uint2((unsigned)l0 | ((unsigned)l1 << 16),
                                            (unsigned)l2 | ((unsigned)l3 << 16));
    }
    asm volatile("s_waitcnt lgkmcnt(0)" ::: "memory");
    __builtin_amdgcn_s_barrier();
    __builtin_amdgcn_sched_barrier(0);

    for (int kb = 0; kb < NKB; ++kb) {
        const int p = kb & 1;

        // (1) B fragment loads for THIS kb (L2-resident; vmcnt-counted)
        const size_t bbase = ((size_t)kb * 512 + wid * 64 + l15) * 32 + lg * 8;
        bf16x8 bh[4], bl[4];
        #pragma unroll
        for (int cf = 0; cf < 4; ++cf) {
            bh[cf] = *(const bf16x8*)(whi + bbase + (size_t)cf * 512);
            bl[cf] = *(const bf16x8*)(wlo + bbase + (size_t)cf * 512);
        }

        // (2) A fragments from LDS buf[p]
        bf16x8 ah[4], al[4];
        #pragma unroll
        for (int rf = 0; rf < 4; ++rf) {
            ah[rf] = *(const bf16x8*)&Ahi[p][aoff[rf]];
            al[rf] = *(const bf16x8*)&Alo[p][aoff[rf]];
        }

        // (3) stage tile kb+1 (loaded 2 phases ago) into buf[p^1]
        if (kb + 1 < NKB) {
            unsigned short h0,h1,h2,h3,l0,l1,l2,l3;
            split_bf16(xq0.x, h0, l0); split_bf16(xq0.y, h1, l1);
            split_bf16(xq0.z, h2, l2); split_bf16(xq0.w, h3, l3);
            *(uint2*)&Ahi[p ^ 1][woff] = make_uint2((unsigned)h0 | ((unsigned)h1 << 16),
                                                    (unsigned)h2 | ((unsigned)h3 << 16));
            *(uint2*)&Alo[p ^ 1][woff] = make_uint2((unsigned)l0 | ((unsigned)l1 << 16),
                                                    (unsigned)l2 | ((unsigned)l3 << 16));
        }

        // (4) rotate pipeline; issue x load for kb+3 (2 MFMA phases to land)
        xq0 = xq1;
        if (kb + 3 < NKB && srow_ok)
            xq1 = *(const float4*)(xrow + (kb + 3) * 32 + sk4);

        // (5) MFMA cluster
        __builtin_amdgcn_s_setprio(1);
        #pragma unroll
        for (int cf = 0; cf < 4; ++cf)
            #pragma unroll
            for (int rf = 0; rf < 4; ++rf)
                acc[rf][cf] = __builtin_amdgcn_mfma_f32_16x16x32_bf16(ah[rf], bh[cf], acc[rf][cf], 0, 0, 0);
        #pragma unroll
        for (int cf = 0; cf < 4; ++cf)
            #pragma unroll
            for (int rf = 0; rf < 4; ++rf)
                acc[rf][cf] = __builtin_amdgcn_mfma_f32_16x16x32_bf16(al[rf], bh[cf], acc[rf][cf], 0, 0, 0);
        #pragma unroll
        for (int cf = 0; cf < 4; ++cf)
            #pragma unroll
            for (int rf = 0; rf < 4; ++rf)
                acc[rf][cf] = __builtin_amdgcn_mfma_f32_16x16x32_bf16(ah[rf], bl[cf], acc[rf][cf], 0, 0, 0);
        __builtin_amdgcn_s_setprio(0);

        // (6) counted-wait barrier: only LDS must drain; vmem stays in flight
        if (kb + 1 < NKB) {
            asm volatile("s_waitcnt lgkmcnt(0)" ::: "memory");
            __builtin_amdgcn_s_barrier();
            __builtin_amdgcn_sched_barrier(0);
        }
    }

    // epilogue: C/D layout col = lane&15, row = (lane>>4)*4 + i  [verified]
    float* const y  = (wid < 4) ? yl : yr;
    const float* bp = (wid < 4) ? b_l : b_r;
    #pragma unroll
    for (int cf = 0; cf < 4; ++cf) {
        const int ocol  = (wid & 3) * 64 + cf * 16 + l15;
        const float bia = bp[ocol];
        #pragma unroll
        for (int rf = 0; rf < 4; ++rf) {
            const int row0 = r0 + rf * 16 + lg * 4;
            #pragma unroll
            for (int i = 0; i < 4; ++i) {
                if (row0 + i < N_NODES)
                    y[(size_t)(row0 + i) * D_OUT + ocol] = acc[rf][cf][i] + bia;
            }
        }
    }
}

// ----------------------------------------------------------- CSR build ----
__global__ void hist_k(const int* __restrict__ ei, unsigned* __restrict__ deg)
{
    const int e = blockIdx.x * 256 + threadIdx.x;
    if (e < N_EDGES) atomicAdd(&deg[ei[N_EDGES + e]], 1u);
}

__global__ void row_start_k(const unsigned* __restrict__ deg,
                            unsigned* __restrict__ row_start,
                            unsigned* __restrict__ cursor,
                            unsigned* __restrict__ total)
{
    const int i    = blockIdx.x * 256 + threadIdx.x;
    const int lane = threadIdx.x & 63;
    const unsigned d = (i < N_NODES) ? deg[i] : 0u;

    unsigned v = d;
    #pragma unroll
    for (int off = 1; off < 64; off <<= 1) {
        unsigned tt = __shfl_up(v, off, 64);
        if (lane >= off) v += tt;
    }
    const unsigned excl = v - d;
    const unsigned wave_total = __shfl(v, 63, 64);

    unsigned base = 0;
    if (lane == 0) base = atomicAdd(total, wave_total);
    base = __shfl(base, 0, 64);

    if (i < N_NODES) {
        row_start[i] = base + excl;
        cursor[i]    = base + excl;
    }
}

__global__ void scatter_k(const int* __restrict__ ei,
                          unsigned* __restrict__ cursor,
                          int* __restrict__ csr_src)
{
    const int e = blockIdx.x * 256 + threadIdx.x;
    if (e >= N_EDGES) return;
    const int dst = ei[N_EDGES + e];
    const unsigned pos = atomicAdd(&cursor[dst], 1u);
    csr_src[pos] = ei[e];   // store SOURCE node id directly
}

// ---------------- fused node aggregate: logits + online softmax + gather --
// one 64-lane wave per dst node; lane owns 4 of 256 dims.
// 4 edges per iteration: 4 independent gathers in flight + 4 interleaved
// shuffle chains; softmax update amortized over the quad.
__global__ __launch_bounds__(256) void node_agg(
    const float* __restrict__ xl, const float* __restrict__ xr,
    const float* __restrict__ att, const int* __restrict__ csr_src,
    const unsigned* __restrict__ row_start, const unsigned* __restrict__ deg,
    const float* __restrict__ bias, float* __restrict__ out)
{
    const int node = (blockIdx.x * blockDim.x + threadIdx.x) >> 6;
    const int lane = threadIdx.x & 63;
    if (node >= N_NODES) return;

    const int start = (int)row_start[node];
    const int cnt   = (int)deg[node];
    const int end   = start + cnt;

    const float4 a  = *(const float4*)(att + lane * 4);
    const float4 r  = *(const float4*)(xr + (size_t)node * D_OUT + lane * 4);

    float  m = -INFINITY;
    float  s = 0.f;
    float4 acc = make_float4(0.f, 0.f, 0.f, 0.f);

#define LOGIT(LV, E) do { \
    float h0 = LV.x + r.x, h1 = LV.y + r.y, h2 = LV.z + r.z, h3 = LV.w + r.w; \
    h0 = h0 > 0.f ? h0 : NEG_SLOPE * h0; \
    h1 = h1 > 0.f ? h1 : NEG_SLOPE * h1; \
    h2 = h2 > 0.f ? h2 : NEG_SLOPE * h2; \
    h3 = h3 > 0.f ? h3 : NEG_SLOPE * h3; \
    E = h0 * a.x + h1 * a.y + h2 * a.z + h3 * a.w; \
} while (0)

#define ONE_EDGE(LV) do { \
    float e0; LOGIT(LV, e0); \
    _Pragma("unroll") \
    for (int off = 32; off > 0; off >>= 1) e0 += __shfl_xor(e0, off, 64); \
    const float m_new = fmaxf(m, e0); \
    const float sc    = __expf(m - m_new); \
    const float p0    = __expf(e0 - m_new); \
    s = s * sc + p0; \
    acc.x = acc.x * sc + p0 * LV.x; \
    acc.y = acc.y * sc + p0 * LV.y; \
    acc.z = acc.z * sc + p0 * LV.z; \
    acc.w = acc.w * sc + p0 * LV.w; \
    m = m_new; \
} while (0)

    float4 l0v = make_float4(0.f,0.f,0.f,0.f), l1v = l0v, l2v = l0v, l3v = l0v;
    if (start     < end) l0v = *(const float4*)(xl + (size_t)csr_src[start]     * D_OUT + lane * 4);
    if (start + 1 < end) l1v = *(const float4*)(xl + (size_t)csr_src[start + 1] * D_OUT + lane * 4);
    if (start + 2 < end) l2v = *(const float4*)(xl + (size_t)csr_src[start + 2] * D_OUT + lane * 4);
    if (start + 3 < end) l3v = *(const float4*)(xl + (size_t)csr_src[start + 3] * D_OUT + lane * 4);

    int j = start;
    for (; j + 3 < end; j += 4) {
        float4 n0 = make_float4(0.f,0.f,0.f,0.f), n1 = n0, n2 = n0, n3 = n0;
        if (j + 4 < end) n0 = *(const float4*)(xl + (size_t)csr_src[j + 4] * D_OUT + lane * 4);
        if (j + 5 < end) n1 = *(const float4*)(xl + (size_t)csr_src[j + 5] * D_OUT + lane * 4);
        if (j + 6 < end) n2 = *(const float4*)(xl + (size_t)csr_src[j + 6] * D_OUT + lane * 4);
        if (j + 7 < end) n3 = *(const float4*)(xl + (size_t)csr_src[j + 7] * D_OUT + lane * 4);

        float e0, e1, e2, e3;
        LOGIT(l0v, e0); LOGIT(l1v, e1); LOGIT(l2v, e2); LOGIT(l3v, e3);
        #pragma unroll
        for (int off = 32; off > 0; off >>= 1) {
            e0 += __shfl_xor(e0, off, 64);
            e1 += __shfl_xor(e1, off, 64);
            e2 += __shfl_xor(e2, off, 64);
            e3 += __shfl_xor(e3, off, 64);
        }

        const float m_new = fmaxf(fmaxf(fmaxf(m, e0), fmaxf(e1, e2)), e3);
        const float sc = __expf(m - m_new);
        const float p0 = __expf(e0 - m_new);
        const float p1 = __expf(e1 - m_new);
        const float p2 = __expf(e2 - m_new);
        const float p3 = __expf(e3 - m_new);
        s = s * sc + p0 + p1 + p2 + p3;
        acc.x = acc.x * sc + p0 * l0v.x + p1 * l1v.x + p2 * l2v.x + p3 * l3v.x;
        acc.y = acc.y * sc + p0 * l0v.y + p1 * l1v.y + p2 * l2v.y + p3 * l3v.y;
        acc.z = acc.z * sc + p0 * l0v.z + p1 * l1v.z + p2 * l2v.z + p3 * l3v.z;
        acc.w = acc.w * sc + p0 * l0v.w + p1 * l1v.w + p2 * l2v.w + p3 * l3v.w;
        m = m_new;

        l0v = n0; l1v = n1; l2v = n2; l3v = n3;
    }
    // tail (<=3 edges), static register indices
    if (j < end) { ONE_EDGE(l0v); ++j; }
    if (j < end) { ONE_EDGE(l1v); ++j; }
    if (j < end) { ONE_EDGE(l2v); ++j; }

    const float inv = 1.f / (s + 1e-16f);
    const float4 bv = *(const float4*)(bias + lane * 4);
    float4 o;
    o.x = acc.x * inv + bv.x; o.y = acc.y * inv + bv.y;
    o.z = acc.z * inv + bv.z; o.w = acc.w * inv + bv.w;
    *(float4*)(out + (size_t)node * D_OUT + lane * 4) = o;

#undef ONE_EDGE
#undef LOGIT
}

// --------------------------------------------------------------- launch ---
extern "C" void kernel_launch(void* const* d_in, const int* in_sizes, int n_in,
                              void* d_out, int out_size, void* d_ws, size_t ws_size,
                              hipStream_t stream)
{
    const float* x   = (const float*)d_in[0];
    const int*   ei  = (const int*)  d_in[1];
    const float* W_l = (const float*)d_in[2];
    const float* b_l = (const float*)d_in[3];
    const float* W_r = (const float*)d_in[4];
    const float* b_r = (const float*)d_in[5];
    const float* att = (const float*)d_in[6];
    const float* bias= (const float*)d_in[7];
    float* out = (float*)d_out;

    // workspace layout (4-byte elements); deg and total adjacent for memset
    float*    xl        = (float*)d_ws;                     // N*256
    float*    xr        = xl + (size_t)N_NODES * D_OUT;     // N*256
    int*      csr_src   = (int*)(xr + (size_t)N_NODES * D_OUT); // E
    unsigned* deg       = (unsigned*)(csr_src + N_EDGES);   // N
    unsigned* total     = deg + N_NODES;                    // 1 (+63 pad)
    unsigned* row_start = total + 64;                       // N
    unsigned* cursor    = row_start + N_NODES;              // N
    unsigned short* whi = (unsigned short*)(cursor + N_NODES); // NKB*512*32 bf16
    unsigned short* wlo = whi + (size_t)NKB * 512 * 32;     // NKB*512*32 bf16

    // 0) pack W_l|W_r into bf16 hi/lo fragment-native layout (~1 MB, L2-resident)
    pack_w<<<(D_IN * 512 + 255) / 256, 256, 0, stream>>>(W_l, W_r, whi, wlo);

    // 1) x_l / x_r dual GEMM on the matrix pipe (bf16x3 fp32-emulation)
    gemm_mfma<<<(N_NODES + 63) / 64, 512, 0, stream>>>(
        x, whi, wlo, b_l, b_r, xl, xr);

    // 2) CSR build (deg+total zeroed by one async memset; graph-capturable)
    hipMemsetAsync(deg, 0, (size_t)(N_NODES + 1) * sizeof(unsigned), stream);
    const int nb_nodes = (N_NODES + 255) / 256;
    const int nb_edges = (N_EDGES + 255) / 256;
    hist_k<<<nb_edges, 256, 0, stream>>>(ei, deg);
    row_start_k<<<nb_nodes, 256, 0, stream>>>(deg, row_start, cursor, total);
    scatter_k<<<nb_edges, 256, 0, stream>>>(ei, cursor, csr_src);

    // 3) fused logits + softmax + aggregate (one wave per node)
    node_agg<<<(N_NODES + 3) / 4, 256, 0, stream>>>(
        xl, xr, att, csr_src, row_start, deg, bias, out);
}

// Round 4
// 945.305 us; speedup vs baseline: 1.4615x; 1.0155x over previous
//
#include <hip/hip_runtime.h>
#include <hip/hip_bf16.h>

#define N_NODES 100000
#define N_EDGES 1600000
#define D_IN    480
#define D_OUT   256
#define NEG_SLOPE 0.2f
#define NKB     (D_IN / 32)   // 15 K-steps of 32

typedef __attribute__((ext_vector_type(8))) short bf16x8;
typedef __attribute__((ext_vector_type(4))) float f32x4;

// ---- fp32 -> bf16 hi/lo split (round-to-nearest-even) --------------------
__device__ __forceinline__ unsigned short f2bf_rn(float f) {
    unsigned u = __float_as_uint(f);
    return (unsigned short)((u + 0x7fffu + ((u >> 16) & 1u)) >> 16);
}

__device__ __forceinline__ void split_bf16(float f, unsigned short& h, unsigned short& l) {
    unsigned u  = __float_as_uint(f);
    unsigned hr = (u + 0x7fffu + ((u >> 16) & 1u)) >> 16;
    h = (unsigned short)hr;
    float fh = __uint_as_float(hr << 16);
    l = f2bf_rn(f - fh);   // f - fh exact in fp32 (Sterbenz)
}

// ---- W pre-pack: [kb][col 0..511][kk 0..31] bf16 hi/lo -------------------
__global__ __launch_bounds__(256) void pack_w(
    const float* __restrict__ Wl, const float* __restrict__ Wr,
    unsigned short* __restrict__ whi, unsigned short* __restrict__ wlo)
{
    const int idx = blockIdx.x * 256 + threadIdx.x;
    if (idx >= D_IN * 512) return;
    const int k   = idx >> 9;
    const int col = idx & 511;
    const float f = (col < 256) ? Wl[(size_t)k * 256 + col]
                                : Wr[(size_t)k * 256 + (col - 256)];
    unsigned short h, l;
    split_bf16(f, h, l);
    const size_t o = ((size_t)((k >> 5) * 512 + col) << 5) | (size_t)(k & 31);
    whi[o] = h; wlo[o] = l;
}

// ---- dual GEMM via bf16x3 MFMA, fully-unrolled pipelined K-loop ----------
// 512 threads = 8 waves; wave w owns 64 rows x 64 cols (w<4 -> x_l, else x_r).
// B double-buffered in registers (issued one K-step ahead, consumed after a
// full MFMA phase + barrier); x 2 tiles ahead in registers; lgkm-only barrier.
__global__ __launch_bounds__(512) void gemm_mfma(
    const float* __restrict__ x,
    const unsigned short* __restrict__ whi,
    const unsigned short* __restrict__ wlo,
    const float* __restrict__ b_l, const float* __restrict__ b_r,
    float* __restrict__ yl, float* __restrict__ yr)
{
    __shared__ __align__(16) unsigned short Ahi[2][64 * 32];
    __shared__ __align__(16) unsigned short Alo[2][64 * 32];

    const int t    = threadIdx.x;
    const int wid  = t >> 6;
    const int lane = t & 63;
    const int r0   = blockIdx.x * 64;

    // staging role: thread -> (row, 4 consecutive k)
    const int srow = t >> 3;
    const int sk4  = (t & 7) * 4;
    const int gr   = r0 + srow;
    const float* xrow   = x + (size_t)gr * D_IN;
    const bool  srow_ok = (gr < N_NODES);

    // swizzled offset (ushort units): row*32 + (g ^ ((row>>1)&3))*8 + (k&7)
    const int woff = srow * 32 + (((sk4 >> 3) ^ ((srow >> 1) & 3)) * 8) + (sk4 & 7);

    const int l15 = lane & 15;
    const int lg  = lane >> 4;

    int aoff[4];
    #pragma unroll
    for (int rf = 0; rf < 4; ++rf) {
        const int row = rf * 16 + l15;
        aoff[rf] = row * 32 + ((lg ^ ((row >> 1) & 3)) * 8);
    }

    f32x4 acc[4][4] = {};
    bf16x8 bhr[2][4], blr[2][4];   // B register double-buffer (parity kb&1)

    const size_t bfrag = ((size_t)wid * 64 + l15) * 32 + lg * 8;

    // ---- prologue: stage tile0; x tiles 1,2 in flight; B(0) in regs ------
    float4 xv  = make_float4(0.f, 0.f, 0.f, 0.f);
    float4 xq0 = make_float4(0.f, 0.f, 0.f, 0.f);
    float4 xq1 = make_float4(0.f, 0.f, 0.f, 0.f);
    if (srow_ok) {
        xv  = *(const float4*)(xrow + sk4);        // tile 0
        xq0 = *(const float4*)(xrow + 32 + sk4);   // tile 1
        xq1 = *(const float4*)(xrow + 64 + sk4);   // tile 2
    }
    {
        unsigned short h0,h1,h2,h3,l0,l1,l2,l3;
        split_bf16(xv.x, h0, l0); split_bf16(xv.y, h1, l1);
        split_bf16(xv.z, h2, l2); split_bf16(xv.w, h3, l3);
        *(uint2*)&Ahi[0][woff] = make_uint2((unsigned)h0 | ((unsigned)h1 << 16),
                                            (unsigned)h2 | ((unsigned)h3 << 16));
        *(uint2*)&Alo[0][woff] = make_uint2((unsigned)l0 | ((unsigned)l1 << 16),
                                            (unsigned)l2 | ((unsigned)l3 << 16));
    }
    #pragma unroll
    for (int cf = 0; cf < 4; ++cf) {
        bhr[0][cf] = *(const bf16x8*)(whi + bfrag + (size_t)cf * 512);
        blr[0][cf] = *(const bf16x8*)(wlo + bfrag + (size_t)cf * 512);
    }
    asm volatile("s_waitcnt lgkmcnt(0)" ::: "memory");
    __builtin_amdgcn_s_barrier();
    __builtin_amdgcn_sched_barrier(0);

    #pragma unroll
    for (int kb = 0; kb < NKB; ++kb) {
        const int p  = kb & 1;   // LDS buffer parity
        const int bp = kb & 1;   // B register parity

        // (1) A fragments from LDS buf[p]
        bf16x8 ah[4], al[4];
        #pragma unroll
        for (int rf = 0; rf < 4; ++rf) {
            ah[rf] = *(const bf16x8*)&Ahi[p][aoff[rf]];
            al[rf] = *(const bf16x8*)&Alo[p][aoff[rf]];
        }

        // (2) issue B loads for kb+1 (consumed after MFMA phase + barrier)
        if (kb + 1 < NKB) {
            const size_t bb = (size_t)(kb + 1) * 512 * 32 + bfrag;
            #pragma unroll
            for (int cf = 0; cf < 4; ++cf) {
                bhr[bp ^ 1][cf] = *(const bf16x8*)(whi + bb + (size_t)cf * 512);
                blr[bp ^ 1][cf] = *(const bf16x8*)(wlo + bb + (size_t)cf * 512);
            }
        }

        // (3) split + stage tile kb+1 into buf[p^1] (covers B-load latency)
        if (kb + 1 < NKB) {
            unsigned short h0,h1,h2,h3,l0,l1,l2,l3;
            split_bf16(xq0.x, h0, l0); split_bf16(xq0.y, h1, l1);
            split_bf16(xq0.z, h2, l2); split_bf16(xq0.w, h3, l3);
            *(uint2*)&Ahi[p ^ 1][woff] = make_uint2((unsigned)h0 | ((unsigned)h1 << 16),
                                                    (unsigned)h2 | ((unsigned)h3 << 16));
            *(uint2*)&Alo[p ^ 1][woff] = make_uint2((unsigned)l0 | ((unsigned)l1 << 16),
                                                    (unsigned)l2 | ((unsigned)l3 << 16));
        }

        // (4) rotate x pipeline; issue tile kb+3 (2 MFMA phases to land)
        xq0 = xq1;
        if (kb + 3 < NKB && srow_ok)
            xq1 = *(const float4*)(xrow + (kb + 3) * 32 + sk4);

        // (5) MFMA cluster on current B regs
        __builtin_amdgcn_s_setprio(1);
        #pragma unroll
        for (int cf = 0; cf < 4; ++cf)
            #pragma unroll
            for (int rf = 0; rf < 4; ++rf)
                acc[rf][cf] = __builtin_amdgcn_mfma_f32_16x16x32_bf16(ah[rf], bhr[bp][cf], acc[rf][cf], 0, 0, 0);
        #pragma unroll
        for (int cf = 0; cf < 4; ++cf)
            #pragma unroll
            for (int rf = 0; rf < 4; ++rf)
                acc[rf][cf] = __builtin_amdgcn_mfma_f32_16x16x32_bf16(al[rf], bhr[bp][cf], acc[rf][cf], 0, 0, 0);
        #pragma unroll
        for (int cf = 0; cf < 4; ++cf)
            #pragma unroll
            for (int rf = 0; rf < 4; ++rf)
                acc[rf][cf] = __builtin_amdgcn_mfma_f32_16x16x32_bf16(ah[rf], blr[bp][cf], acc[rf][cf], 0, 0, 0);
        __builtin_amdgcn_s_setprio(0);

        // (6) lgkm-only barrier (ds_writes drained; vmem stays in flight)
        if (kb + 1 < NKB) {
            asm volatile("s_waitcnt lgkmcnt(0)" ::: "memory");
            __builtin_amdgcn_s_barrier();
            __builtin_amdgcn_sched_barrier(0);
        }
    }

    // epilogue: C/D layout col = lane&15, row = (lane>>4)*4 + i  [verified]
    float* const y  = (wid < 4) ? yl : yr;
    const float* bp2 = (wid < 4) ? b_l : b_r;
    #pragma unroll
    for (int cf = 0; cf < 4; ++cf) {
        const int ocol  = (wid & 3) * 64 + cf * 16 + l15;
        const float bia = bp2[ocol];
        #pragma unroll
        for (int rf = 0; rf < 4; ++rf) {
            const int row0 = r0 + rf * 16 + lg * 4;
            #pragma unroll
            for (int i = 0; i < 4; ++i) {
                if (row0 + i < N_NODES)
                    y[(size_t)(row0 + i) * D_OUT + ocol] = acc[rf][cf][i] + bia;
            }
        }
    }
}

// ----------------------------------------------------------- CSR build ----
__global__ void hist_k(const int* __restrict__ ei, unsigned* __restrict__ deg)
{
    const int e = blockIdx.x * 256 + threadIdx.x;
    if (e < N_EDGES) atomicAdd(&deg[ei[N_EDGES + e]], 1u);
}

__global__ void row_start_k(const unsigned* __restrict__ deg,
                            unsigned* __restrict__ row_start,
                            unsigned* __restrict__ cursor,
                            unsigned* __restrict__ total)
{
    const int i    = blockIdx.x * 256 + threadIdx.x;
    const int lane = threadIdx.x & 63;
    const unsigned d = (i < N_NODES) ? deg[i] : 0u;

    unsigned v = d;
    #pragma unroll
    for (int off = 1; off < 64; off <<= 1) {
        unsigned tt = __shfl_up(v, off, 64);
        if (lane >= off) v += tt;
    }
    const unsigned excl = v - d;
    const unsigned wave_total = __shfl(v, 63, 64);

    unsigned base = 0;
    if (lane == 0) base = atomicAdd(total, wave_total);
    base = __shfl(base, 0, 64);

    if (i < N_NODES) {
        row_start[i] = base + excl;
        cursor[i]    = base + excl;
    }
}

__global__ void scatter_k(const int* __restrict__ ei,
                          unsigned* __restrict__ cursor,
                          int* __restrict__ csr_src)
{
    const int e = blockIdx.x * 256 + threadIdx.x;
    if (e >= N_EDGES) return;
    const int dst = ei[N_EDGES + e];
    const unsigned pos = atomicAdd(&cursor[dst], 1u);
    csr_src[pos] = ei[e];   // store SOURCE node id directly
}

// ---------------- fused node aggregate: logits + online softmax + gather --
// one 64-lane wave per dst node; lane owns 4 of 256 dims.
// 4 edges/iter; packed-fold wave reduce (10 DS ops vs 24); rescale skipped
// when the running max doesn't grow; scalarized csr index loads.
__global__ __launch_bounds__(256) void node_agg(
    const float* __restrict__ xl, const float* __restrict__ xr,
    const float* __restrict__ att, const int* __restrict__ csr_src,
    const unsigned* __restrict__ row_start, const unsigned* __restrict__ deg,
    const float* __restrict__ bias, float* __restrict__ out)
{
    const int node = (blockIdx.x * blockDim.x + threadIdx.x) >> 6;
    const int lane = threadIdx.x & 63;
    if (node >= N_NODES) return;

    const int start = (int)row_start[node];
    const int cnt   = (int)deg[node];
    const int end   = start + cnt;

    const float4 a  = *(const float4*)(att + lane * 4);
    const float4 r  = *(const float4*)(xr + (size_t)node * D_OUT + lane * 4);

    float  m = -INFINITY;
    float  s = 0.f;
    float4 acc = make_float4(0.f, 0.f, 0.f, 0.f);

#define LOGIT(LV, E) do { \
    float h0 = LV.x + r.x, h1 = LV.y + r.y, h2 = LV.z + r.z, h3 = LV.w + r.w; \
    h0 = h0 > 0.f ? h0 : NEG_SLOPE * h0; \
    h1 = h1 > 0.f ? h1 : NEG_SLOPE * h1; \
    h2 = h2 > 0.f ? h2 : NEG_SLOPE * h2; \
    h3 = h3 > 0.f ? h3 : NEG_SLOPE * h3; \
    E = h0 * a.x + h1 * a.y + h2 * a.z + h3 * a.w; \
} while (0)

#define ONE_EDGE(LV) do { \
    float e0; LOGIT(LV, e0); \
    _Pragma("unroll") \
    for (int off = 32; off > 0; off >>= 1) e0 += __shfl_xor(e0, off, 64); \
    const float m_new = fmaxf(m, e0); \
    if (m_new > m) { \
        const float sc = __expf(m - m_new); \
        s *= sc; acc.x *= sc; acc.y *= sc; acc.z *= sc; acc.w *= sc; \
        m = m_new; \
    } \
    const float p0 = __expf(e0 - m); \
    s += p0; \
    acc.x += p0 * LV.x; acc.y += p0 * LV.y; \
    acc.z += p0 * LV.z; acc.w += p0 * LV.w; \
} while (0)

    float4 l0v = make_float4(0.f,0.f,0.f,0.f), l1v = l0v, l2v = l0v, l3v = l0v;
    if (start     < end) l0v = *(const float4*)(xl + (size_t)csr_src[start]     * D_OUT + lane * 4);
    if (start + 1 < end) l1v = *(const float4*)(xl + (size_t)csr_src[start + 1] * D_OUT + lane * 4);
    if (start + 2 < end) l2v = *(const float4*)(xl + (size_t)csr_src[start + 2] * D_OUT + lane * 4);
    if (start + 3 < end) l3v = *(const float4*)(xl + (size_t)csr_src[start + 3] * D_OUT + lane * 4);

    const int pb = lane & 1;         // fold parity bits
    const int qb = lane & 2;
    const int c  = lane & 3;         // fold class

    int j = start;
    for (; j + 3 < end; j += 4) {
        // prefetch next 4 source indices (scalar) and gathers
        const int ju = __builtin_amdgcn_readfirstlane(j);
        float4 n0 = make_float4(0.f,0.f,0.f,0.f), n1 = n0, n2 = n0, n3 = n0;
        if (j + 4 < end) n0 = *(const float4*)(xl + (size_t)csr_src[ju + 4] * D_OUT + lane * 4);
        if (j + 5 < end) n1 = *(const float4*)(xl + (size_t)csr_src[ju + 5] * D_OUT + lane * 4);
        if (j + 6 < end) n2 = *(const float4*)(xl + (size_t)csr_src[ju + 6] * D_OUT + lane * 4);
        if (j + 7 < end) n3 = *(const float4*)(xl + (size_t)csr_src[ju + 7] * D_OUT + lane * 4);

        float e0, e1, e2, e3;
        LOGIT(l0v, e0); LOGIT(l1v, e1); LOGIT(l2v, e2); LOGIT(l3v, e3);

        // packed-fold reduce: class c = lane&3 accumulates S_c
        float z  = pb ? e1 : e0;
        float zo = pb ? e0 : e1;
        z += __shfl_xor(zo, 1, 64);
        float w  = pb ? e3 : e2;
        float wo = pb ? e2 : e3;
        w += __shfl_xor(wo, 1, 64);
        float v  = qb ? w : z;
        float vo = qb ? z : w;
        v += __shfl_xor(vo, 2, 64);
        #pragma unroll
        for (int off = 4; off < 64; off <<= 1) v += __shfl_xor(v, off, 64);
        // gather all four sums: r_k = S_{c^k}  =>  S_j = arr[c^j]
        const float r1 = __shfl_xor(v, 1, 64);
        const float r2 = __shfl_xor(v, 2, 64);
        const float r3 = __shfl_xor(v, 3, 64);
        const float t01  = pb ? r1 : v;    // arr[(c&1)]   pair {v,r1}
        const float t01f = pb ? v  : r1;   // arr[(c&1)^1]
        const float t23  = pb ? r3 : r2;   // pair {r2,r3}
        const float t23f = pb ? r2 : r3;
        const float S0 = qb ? t23  : t01;
        const float S1 = qb ? t23f : t01f;
        const float S2 = qb ? t01  : t23;
        const float S3 = qb ? t01f : t23f;

        const float m_new = fmaxf(m, fmaxf(fmaxf(v, r1), fmaxf(r2, r3)));
        if (m_new > m) {
            const float sc = __expf(m - m_new);
            s *= sc; acc.x *= sc; acc.y *= sc; acc.z *= sc; acc.w *= sc;
            m = m_new;
        }
        const float p0 = __expf(S0 - m);
        const float p1 = __expf(S1 - m);
        const float p2 = __expf(S2 - m);
        const float p3 = __expf(S3 - m);
        s += p0 + p1 + p2 + p3;
        acc.x += p0 * l0v.x + p1 * l1v.x + p2 * l2v.x + p3 * l3v.x;
        acc.y += p0 * l0v.y + p1 * l1v.y + p2 * l2v.y + p3 * l3v.y;
        acc.z += p0 * l0v.z + p1 * l1v.z + p2 * l2v.z + p3 * l3v.z;
        acc.w += p0 * l0v.w + p1 * l1v.w + p2 * l2v.w + p3 * l3v.w;

        l0v = n0; l1v = n1; l2v = n2; l3v = n3;
    }
    // tail (<=3 edges), static register indices
    if (j < end) { ONE_EDGE(l0v); ++j; }
    if (j < end) { ONE_EDGE(l1v); ++j; }
    if (j < end) { ONE_EDGE(l2v); ++j; }

    const float inv = 1.f / (s + 1e-16f);
    const float4 bv = *(const float4*)(bias + lane * 4);
    float4 o;
    o.x = acc.x * inv + bv.x; o.y = acc.y * inv + bv.y;
    o.z = acc.z * inv + bv.z; o.w = acc.w * inv + bv.w;
    *(float4*)(out + (size_t)node * D_OUT + lane * 4) = o;

#undef ONE_EDGE
#undef LOGIT
}

// --------------------------------------------------------------- launch ---
extern "C" void kernel_launch(void* const* d_in, const int* in_sizes, int n_in,
                              void* d_out, int out_size, void* d_ws, size_t ws_size,
                              hipStream_t stream)
{
    const float* x   = (const float*)d_in[0];
    const int*   ei  = (const int*)  d_in[1];
    const float* W_l = (const float*)d_in[2];
    const float* b_l = (const float*)d_in[3];
    const float* W_r = (const float*)d_in[4];
    const float* b_r = (const float*)d_in[5];
    const float* att = (const float*)d_in[6];
    const float* bias= (const float*)d_in[7];
    float* out = (float*)d_out;

    // workspace layout (4-byte elements); deg and total adjacent for memset
    float*    xl        = (float*)d_ws;                     // N*256
    float*    xr        = xl + (size_t)N_NODES * D_OUT;     // N*256
    int*      csr_src   = (int*)(xr + (size_t)N_NODES * D_OUT); // E
    unsigned* deg       = (unsigned*)(csr_src + N_EDGES);   // N
    unsigned* total     = deg + N_NODES;                    // 1 (+63 pad)
    unsigned* row_start = total + 64;                       // N
    unsigned* cursor    = row_start + N_NODES;              // N
    unsigned short* whi = (unsigned short*)(cursor + N_NODES); // NKB*512*32 bf16
    unsigned short* wlo = whi + (size_t)NKB * 512 * 32;     // NKB*512*32 bf16

    // 0) pack W_l|W_r into bf16 hi/lo fragment-native layout (~1 MB, L2-resident)
    pack_w<<<(D_IN * 512 + 255) / 256, 256, 0, stream>>>(W_l, W_r, whi, wlo);

    // 1) x_l / x_r dual GEMM on the matrix pipe (bf16x3 fp32-emulation)
    gemm_mfma<<<(N_NODES + 63) / 64, 512, 0, stream>>>(
        x, whi, wlo, b_l, b_r, xl, xr);

    // 2) CSR build (deg+total zeroed by one async memset; graph-capturable)
    hipMemsetAsync(deg, 0, (size_t)(N_NODES + 1) * sizeof(unsigned), stream);
    const int nb_nodes = (N_NODES + 255) / 256;
    const int nb_edges = (N_EDGES + 255) / 256;
    hist_k<<<nb_edges, 256, 0, stream>>>(ei, deg);
    row_start_k<<<nb_nodes, 256, 0, stream>>>(deg, row_start, cursor, total);
    scatter_k<<<nb_edges, 256, 0, stream>>>(ei, cursor, csr_src);

    // 3) fused logits + softmax + aggregate (one wave per node)
    node_agg<<<(N_NODES + 3) / 4, 256, 0, stream>>>(
        xl, xr, att, csr_src, row_start, deg, bias, out);
}